// Round 5
// baseline (1311.058 us; speedup 1.0000x reference)
//
#include <hip/hip_runtime.h>

#define N_NODES 50000
#define HID 128
#define NE 1600000
#define NH (N_NODES * HID)      // 6,400,000 floats per [N,HID] buffer

#define EPB   4096              // edges per K1/K3 block
#define NBLK1 391               // ceil(NE / EPB)
#define NBUK  391               // ceil(N_NODES / 128) row buckets (128 rows each)
#define TBL   (NBUK * NBLK1)    // 152,881 scan table entries
#define SB    ((TBL + 255) / 256)  // 598 scan blocks

#define RB    8                 // rows per batch in fused tail
#define RPB   80                // rows per block in fused tail (625 blocks)

// ===========================================================================
// K1: per-block LDS histogram over 391 coarse buckets + per-edge rank.
// ===========================================================================
__global__ __launch_bounds__(256) void k1_hist(
    const int* __restrict__ rows, int* __restrict__ table,
    unsigned short* __restrict__ rank)
{
    __shared__ int h[NBUK];
    int b = blockIdx.x, t = threadIdx.x;
    for (int i = t; i < NBUK; i += 256) h[i] = 0;
    __syncthreads();
    int e0 = b * EPB;
    int e1 = min(e0 + EPB, NE);
    for (int e = e0 + t; e < e1; e += 256)
        rank[e] = (unsigned short)atomicAdd(&h[rows[e] >> 7], 1);
    __syncthreads();
    for (int i = t; i < NBUK; i += 256) table[i * NBLK1 + b] = h[i];
}

// ===========================================================================
// S1/S2/S3: hierarchical exclusive scan of table[TBL] (bucket-major)
// ===========================================================================
__global__ __launch_bounds__(256) void s1_partial(
    const int* __restrict__ table, int* __restrict__ part)
{
    __shared__ int red[256];
    int b = blockIdx.x, t = threadIdx.x;
    int idx = b * 256 + t;
    red[t] = (idx < TBL) ? table[idx] : 0;
    __syncthreads();
    #pragma unroll
    for (int s = 128; s > 0; s >>= 1) {
        if (t < s) red[t] += red[t + s];
        __syncthreads();
    }
    if (t == 0) part[b] = red[0];
}

__global__ __launch_bounds__(1024) void s2_scan(int* __restrict__ part)
{
    __shared__ int sh[1024];
    int t = threadIdx.x;
    sh[t] = (t < SB) ? part[t] : 0;
    __syncthreads();
    for (int off = 1; off < 1024; off <<= 1) {
        int v = (t >= off) ? sh[t - off] : 0;
        __syncthreads();
        sh[t] += v;
        __syncthreads();
    }
    if (t < SB) part[t] = (t == 0) ? 0 : sh[t - 1];
}

__global__ __launch_bounds__(256) void s3_add(
    int* __restrict__ table, const int* __restrict__ part)
{
    __shared__ int sh[256];
    int b = blockIdx.x, t = threadIdx.x;
    int idx = b * 256 + t;
    int v = (idx < TBL) ? table[idx] : 0;
    sh[t] = v;
    __syncthreads();
    #pragma unroll
    for (int off = 1; off < 256; off <<= 1) {
        int u = (t >= off) ? sh[t - off] : 0;
        __syncthreads();
        sh[t] += u;
        __syncthreads();
    }
    int excl = (t == 0) ? 0 : sh[t - 1];
    if (idx < TBL) table[idx] = part[b] + excl;
}

// ===========================================================================
// K3: atomic-free scatter into bucket-partitioned tmp.
// word0 = (row&127)<<16 | col  (col < 65536), word1 = val bits.
// ===========================================================================
__global__ __launch_bounds__(256) void k3_scatter(
    const int* __restrict__ rows, const int* __restrict__ cols,
    const float* __restrict__ vals, const unsigned short* __restrict__ rank,
    const int* __restrict__ table, int2* __restrict__ tmp)
{
    __shared__ int base[NBUK];
    int b = blockIdx.x, t = threadIdx.x;
    for (int i = t; i < NBUK; i += 256) base[i] = table[i * NBLK1 + b];
    __syncthreads();
    int e0 = b * EPB;
    int e1 = min(e0 + EPB, NE);
    for (int e = e0 + t; e < e1; e += 256) {
        int r = rows[e];
        int pos = base[r >> 7] + (int)rank[e];
        tmp[pos] = make_int2(((r & 127) << 16) | cols[e], __float_as_int(vals[e]));
    }
}

// ===========================================================================
// K4: per-bucket fine sort (128 rows) -> final CSR pairs + rowptr.
// ===========================================================================
__global__ __launch_bounds__(256) void k4_fine(
    const int* __restrict__ table, const int2* __restrict__ tmp,
    int2* __restrict__ pairs, int* __restrict__ rowptr)
{
    __shared__ int cnt[128];
    __shared__ int sh[256];
    __shared__ int nxt[128];
    int k = blockIdx.x, t = threadIdx.x;
    if (t < 128) cnt[t] = 0;
    __syncthreads();
    int base = table[k * NBLK1];
    int end  = (k == NBUK - 1) ? NE : table[(k + 1) * NBLK1];
    for (int e = base + t; e < end; e += 256)
        atomicAdd(&cnt[(tmp[e].x >> 16) & 127], 1);
    __syncthreads();
    sh[t] = (t < 128) ? cnt[t] : 0;
    __syncthreads();
    #pragma unroll
    for (int off = 1; off < 256; off <<= 1) {
        int v = (t >= off) ? sh[t - off] : 0;
        __syncthreads();
        sh[t] += v;
        __syncthreads();
    }
    if (t < 128) {
        int excl = (t == 0) ? 0 : sh[t - 1];
        nxt[t] = base + excl;
        int row = k * 128 + t;
        if (row < N_NODES) rowptr[row] = base + excl;
    }
    if (k == NBUK - 1 && t == 255) rowptr[N_NODES] = NE;
    __syncthreads();
    for (int e = base + t; e < end; e += 256) {
        int2 p = tmp[e];
        int pos = atomicAdd(&nxt[(p.x >> 16) & 127], 1);
        pairs[pos] = make_int2(p.x & 0xFFFF, p.y);
    }
}

// ===========================================================================
// CSR SpMM (gather form, no atomics): y[r,:] = sum_e val_e * x[col_e,:]
// ===========================================================================
template <bool ABS>
__global__ __launch_bounds__(256) void csr_spmm_kernel(
    const int* __restrict__ rowptr, const int2* __restrict__ pairs,
    const float* __restrict__ x, float* __restrict__ y)
{
    int t   = blockIdx.x * 256 + threadIdx.x;
    int r   = t >> 5;
    int sub = t & 31;
    if (r >= N_NODES) return;

    const float4* x4 = (const float4*)x;
    int start = rowptr[r], end = rowptr[r + 1];

    float4 a0 = {0.f, 0.f, 0.f, 0.f};
    float4 a1 = {0.f, 0.f, 0.f, 0.f};
    float4 a2 = {0.f, 0.f, 0.f, 0.f};
    float4 a3 = {0.f, 0.f, 0.f, 0.f};
    int e = start;
    for (; e + 3 < end; e += 4) {
        int2 p0 = pairs[e];
        int2 p1 = pairs[e + 1];
        int2 p2 = pairs[e + 2];
        int2 p3 = pairs[e + 3];
        float4 x0 = x4[(size_t)p0.x * 32 + sub];
        float4 x1 = x4[(size_t)p1.x * 32 + sub];
        float4 x2 = x4[(size_t)p2.x * 32 + sub];
        float4 x3 = x4[(size_t)p3.x * 32 + sub];
        float v0 = __int_as_float(p0.y);
        float v1 = __int_as_float(p1.y);
        float v2 = __int_as_float(p2.y);
        float v3 = __int_as_float(p3.y);
        a0.x += v0 * x0.x; a0.y += v0 * x0.y; a0.z += v0 * x0.z; a0.w += v0 * x0.w;
        a1.x += v1 * x1.x; a1.y += v1 * x1.y; a1.z += v1 * x1.z; a1.w += v1 * x1.w;
        a2.x += v2 * x2.x; a2.y += v2 * x2.y; a2.z += v2 * x2.z; a2.w += v2 * x2.w;
        a3.x += v3 * x3.x; a3.y += v3 * x3.y; a3.z += v3 * x3.z; a3.w += v3 * x3.w;
    }
    for (; e < end; ++e) {
        int2 p0 = pairs[e];
        float4 x0 = x4[(size_t)p0.x * 32 + sub];
        float v0 = __int_as_float(p0.y);
        a0.x += v0 * x0.x; a0.y += v0 * x0.y; a0.z += v0 * x0.z; a0.w += v0 * x0.w;
    }
    float4 acc;
    acc.x = (a0.x + a1.x) + (a2.x + a3.x);
    acc.y = (a0.y + a1.y) + (a2.y + a3.y);
    acc.z = (a0.z + a1.z) + (a2.z + a3.z);
    acc.w = (a0.w + a1.w) + (a2.w + a3.w);
    if (ABS) {
        acc.x = fabsf(acc.x); acc.y = fabsf(acc.y);
        acc.z = fabsf(acc.z); acc.w = fabsf(acc.w);
    }
    ((float4*)(y + (size_t)r * HID))[sub] = acc;
}

// ===========================================================================
// Attention: e[n,b] = dot(relu(pair_b[n]), a); att = softmax over b (6)
// ===========================================================================
__global__ __launch_bounds__(256) void attn_kernel(
    const float* __restrict__ X, const float* __restrict__ B,
    const float* __restrict__ a, float* __restrict__ att)
{
    int wid  = (blockIdx.x * 256 + threadIdx.x) >> 6;
    int lane = threadIdx.x & 63;
    if (wid >= N_NODES) return;

    const float4 av = ((const float4*)a)[lane];
    float e[6];

    if (wid < N_NODES / 2) {
        const float4 p = ((const float4*)(X + (size_t)wid * 256))[lane];
        float s = fmaxf(p.x, 0.f) * av.x + fmaxf(p.y, 0.f) * av.y +
                  fmaxf(p.z, 0.f) * av.z + fmaxf(p.w, 0.f) * av.w;
        #pragma unroll
        for (int m = 1; m < 64; m <<= 1) s += __shfl_xor(s, m);
        #pragma unroll
        for (int b = 0; b < 6; ++b) e[b] = s;
    } else {
        int m = 2 * wid - N_NODES;
        #pragma unroll
        for (int b = 0; b < 6; ++b) {
            const float4 p =
                ((const float4*)(B + (size_t)b * NH + (size_t)m * HID))[lane];
            float s = fmaxf(p.x, 0.f) * av.x + fmaxf(p.y, 0.f) * av.y +
                      fmaxf(p.z, 0.f) * av.z + fmaxf(p.w, 0.f) * av.w;
            #pragma unroll
            for (int k = 1; k < 64; k <<= 1) s += __shfl_xor(s, k);
            e[b] = s;
        }
    }

    if (lane == 0) {
        float mx = e[0];
        #pragma unroll
        for (int b = 1; b < 6; ++b) mx = fmaxf(mx, e[b]);
        float ex[6], sum = 0.f;
        #pragma unroll
        for (int b = 0; b < 6; ++b) { ex[b] = expf(e[b] - mx); sum += ex[b]; }
        float inv = 1.f / sum;
        #pragma unroll
        for (int b = 0; b < 6; ++b) att[(size_t)wid * 6 + b] = ex[b] * inv;
    }
}

// ===========================================================================
// Fused tail: hprime + FC1 + FC2 in one kernel.
// Each lane of a 4-wave block holds one W row in 128 VGPRs:
//   waves 0,1 -> W1 rows o = (wave&1)*64+lane;  waves 2,3 -> W2 rows.
// Per 8-row batch: all threads stage hp rows (hprime math) into LDS,
// barrier, waves 0-1 run layer1 -> mid LDS, waves 2-3 run layer2 of the
// PREVIOUS batch (double-buffered mid, one barrier per batch).
// 625 blocks x 80 rows = 50000. d_out is write-only (no in-place hazard).
// ===========================================================================
__global__ __launch_bounds__(256) void fused_tail_kernel(
    const float* __restrict__ B, const float* __restrict__ att,
    const float* __restrict__ W1, const float* __restrict__ b1,
    const float* __restrict__ W2, const float* __restrict__ b2,
    float* __restrict__ out)
{
    __shared__ float xb[2][RB][HID];   // staged hp rows
    __shared__ float mb[2][RB][HID];   // mid rows (layer1 output)

    const int t    = threadIdx.x;
    const int wave = t >> 6;
    const int lane = t & 63;
    const int o    = (wave & 1) * 64 + lane;

    // --- load my W row into registers (static indexing only) ---
    float wreg[HID];
    {
        const float* Wsrc = (wave < 2) ? W1 : W2;
        const float4* wr  = (const float4*)(Wsrc + (size_t)o * HID);
        #pragma unroll
        for (int k4 = 0; k4 < 32; ++k4) {
            float4 v = wr[k4];
            wreg[k4 * 4 + 0] = v.x;
            wreg[k4 * 4 + 1] = v.y;
            wreg[k4 * 4 + 2] = v.z;
            wreg[k4 * 4 + 3] = v.w;
        }
    }
    const float bias = ((wave < 2) ? b1 : b2)[o];
    const int row0 = blockIdx.x * RPB;
    const int NBATCH = RPB / RB;   // 10

    for (int j = 0; j <= NBATCH; ++j) {
        const int cur = j & 1;

        // ---- stage: hprime math for batch j -> xb[cur] ----
        if (j < NBATCH) {
            const int base = row0 + j * RB;
            #pragma unroll
            for (int i2 = 0; i2 < (RB * HID) / 256; ++i2) {
                int i = i2 * 256 + t;
                int r = i >> 7, q = i & 127;
                int n = base + r;
                float s = 0.f;
                #pragma unroll
                for (int p = 0; p < 6; ++p) {
                    int f  = p * HID + q;
                    int jj = f % 6;
                    int ii = f / 6;
                    s += att[(size_t)n * 6 + p] *
                         B[(size_t)jj * NH + (size_t)n * HID + ii];
                }
                xb[cur][r][q] = s * (1.0f / 6.0f);
            }
        }
        __syncthreads();

        if (wave < 2) {
            // ---- layer 1 on batch j: xb[cur] -> mb[cur] ----
            if (j < NBATCH) {
                float acc[RB];
                #pragma unroll
                for (int r = 0; r < RB; ++r) acc[r] = 0.f;
                #pragma unroll
                for (int k4 = 0; k4 < 32; ++k4) {
                    float wx = wreg[k4 * 4 + 0], wy = wreg[k4 * 4 + 1];
                    float wz = wreg[k4 * 4 + 2], ww = wreg[k4 * 4 + 3];
                    #pragma unroll
                    for (int r = 0; r < RB; ++r) {
                        float4 xv = *(const float4*)&xb[cur][r][k4 * 4];
                        acc[r] += wx * xv.x + wy * xv.y + wz * xv.z + ww * xv.w;
                    }
                }
                #pragma unroll
                for (int r = 0; r < RB; ++r) {
                    float v = acc[r] + bias;
                    v = v > 0.f ? v : 0.01f * v;
                    mb[cur][r][o] = v;
                }
            }
        } else {
            // ---- layer 2 on batch j-1: mb[cur^1] -> out ----
            if (j > 0) {
                const int base = row0 + (j - 1) * RB;
                float acc[RB];
                #pragma unroll
                for (int r = 0; r < RB; ++r) acc[r] = 0.f;
                #pragma unroll
                for (int k4 = 0; k4 < 32; ++k4) {
                    float wx = wreg[k4 * 4 + 0], wy = wreg[k4 * 4 + 1];
                    float wz = wreg[k4 * 4 + 2], ww = wreg[k4 * 4 + 3];
                    #pragma unroll
                    for (int r = 0; r < RB; ++r) {
                        float4 xv = *(const float4*)&mb[cur ^ 1][r][k4 * 4];
                        acc[r] += wx * xv.x + wy * xv.y + wz * xv.z + ww * xv.w;
                    }
                }
                #pragma unroll
                for (int r = 0; r < RB; ++r) {
                    float v = acc[r] + bias;
                    v = v > 0.f ? v : 0.01f * v;
                    out[(size_t)(base + r) * HID + o] = v;
                }
            }
        }
    }
}

// ===========================================================================
extern "C" void kernel_launch(void* const* d_in, const int* in_sizes, int n_in,
                              void* d_out, int out_size, void* d_ws, size_t ws_size,
                              hipStream_t stream)
{
    const float* X  = (const float*)d_in[0];
    const float* a  = (const float*)d_in[1];
    const float* W1 = (const float*)d_in[2];
    const float* b1 = (const float*)d_in[3];
    const float* W2 = (const float*)d_in[4];
    const float* b2 = (const float*)d_in[5];
    const int*   op_rows[4] = { (const int*)d_in[6],  (const int*)d_in[9],
                                (const int*)d_in[12], (const int*)d_in[15] };
    const int*   op_cols[4] = { (const int*)d_in[7],  (const int*)d_in[10],
                                (const int*)d_in[13], (const int*)d_in[16] };
    const float* op_vals[4] = { (const float*)d_in[8],  (const float*)d_in[11],
                                (const float*)d_in[14], (const float*)d_in[17] };
    // d_in[18..20] = Psct (unused: withgres=False)

    // ---- workspace layout (4-byte words, keep int2 buffers 8B-aligned) ----
    float* ws = (float*)d_ws;
    float* B     = ws;                                     // 6*NH
    float* att   = B + (size_t)6 * NH;                     // 6*N
    int*   ptr   = (int*)(att + (size_t)6 * N_NODES);      // N+2
    int*   table = ptr + N_NODES + 2;                      // TBL (pad to even)
    int*   part  = table + TBL + 1;                        // 1024
    unsigned short* brnk = (unsigned short*)(part + 1024); // NE ushort = NE/2 words
    int2*  tmp   = (int2*)((int*)brnk + NE / 2);           // NE int2
    int2*  pairs = tmp + NE;                               // NE int2 (shared by all ops)

    dim3 blk(256);
    const int rg = (N_NODES * 32 + 255) / 256;  // 6250

    // sorts one operator into (pairs, ptr) — no global atomics anywhere
    auto sort_op = [&](int o) {
        k1_hist<<<NBLK1, blk, 0, stream>>>(op_rows[o], table, brnk);
        s1_partial<<<SB, blk, 0, stream>>>(table, part);
        s2_scan<<<1, 1024, 0, stream>>>(part);
        s3_add<<<SB, blk, 0, stream>>>(table, part);
        k3_scatter<<<NBLK1, blk, 0, stream>>>(op_rows[o], op_cols[o], op_vals[o],
                                              brnk, table, tmp);
        k4_fine<<<NBUK, blk, 0, stream>>>(table, tmp, pairs, ptr);
    };

    // ---- A: sort, then 3 chained hops (CSR dead afterwards -> P's reuse) ----
    sort_op(0);
    csr_spmm_kernel<false><<<rg, blk, 0, stream>>>(ptr, pairs, X,               B + 0 * (size_t)NH);
    csr_spmm_kernel<false><<<rg, blk, 0, stream>>>(ptr, pairs, B + 0 * (size_t)NH, B + 1 * (size_t)NH);
    csr_spmm_kernel<false><<<rg, blk, 0, stream>>>(ptr, pairs, B + 1 * (size_t)NH, B + 2 * (size_t)NH);

    // ---- P1..P3: sort (reusing buffers), spmm with fused abs ----
    for (int i = 0; i < 3; ++i) {
        sort_op(1 + i);
        csr_spmm_kernel<true><<<rg, blk, 0, stream>>>(ptr, pairs, X, B + (size_t)(3 + i) * NH);
    }

    // ---- attention, then fused hprime+FC1+FC2 ----
    attn_kernel<<<(N_NODES + 3) / 4, blk, 0, stream>>>(X, B, a, att);
    fused_tail_kernel<<<N_NODES / RPB, blk, 0, stream>>>(B, att, W1, b1, W2, b2,
                                                         (float*)d_out);
}

// Round 6
// 1114.408 us; speedup vs baseline: 1.1765x; 1.1765x over previous
//
#include <hip/hip_runtime.h>

#define N_NODES 50000
#define HID 128
#define NE 1600000
#define NH (N_NODES * HID)      // 6,400,000 floats per [N,HID] buffer

#define EPB   4096              // edges per K1/K3 block
#define NBLK1 391               // ceil(NE / EPB)
#define NBUK  391               // ceil(N_NODES / 128) row buckets (128 rows each)
#define TBL   (NBUK * NBLK1)    // 152,881 scan table entries
#define SB    ((TBL + 255) / 256)  // 598 scan blocks

// ===========================================================================
// K1: per-block LDS histogram over 391 coarse buckets + per-edge rank.
// ===========================================================================
__global__ __launch_bounds__(256) void k1_hist(
    const int* __restrict__ rows, int* __restrict__ table,
    unsigned short* __restrict__ rank)
{
    __shared__ int h[NBUK];
    int b = blockIdx.x, t = threadIdx.x;
    for (int i = t; i < NBUK; i += 256) h[i] = 0;
    __syncthreads();
    int e0 = b * EPB;
    int e1 = min(e0 + EPB, NE);
    for (int e = e0 + t; e < e1; e += 256)
        rank[e] = (unsigned short)atomicAdd(&h[rows[e] >> 7], 1);
    __syncthreads();
    for (int i = t; i < NBUK; i += 256) table[i * NBLK1 + b] = h[i];
}

// ===========================================================================
// S1/S2/S3: hierarchical exclusive scan of table[TBL] (bucket-major)
// ===========================================================================
__global__ __launch_bounds__(256) void s1_partial(
    const int* __restrict__ table, int* __restrict__ part)
{
    __shared__ int red[256];
    int b = blockIdx.x, t = threadIdx.x;
    int idx = b * 256 + t;
    red[t] = (idx < TBL) ? table[idx] : 0;
    __syncthreads();
    #pragma unroll
    for (int s = 128; s > 0; s >>= 1) {
        if (t < s) red[t] += red[t + s];
        __syncthreads();
    }
    if (t == 0) part[b] = red[0];
}

__global__ __launch_bounds__(1024) void s2_scan(int* __restrict__ part)
{
    __shared__ int sh[1024];
    int t = threadIdx.x;
    sh[t] = (t < SB) ? part[t] : 0;
    __syncthreads();
    for (int off = 1; off < 1024; off <<= 1) {
        int v = (t >= off) ? sh[t - off] : 0;
        __syncthreads();
        sh[t] += v;
        __syncthreads();
    }
    if (t < SB) part[t] = (t == 0) ? 0 : sh[t - 1];
}

__global__ __launch_bounds__(256) void s3_add(
    int* __restrict__ table, const int* __restrict__ part)
{
    __shared__ int sh[256];
    int b = blockIdx.x, t = threadIdx.x;
    int idx = b * 256 + t;
    int v = (idx < TBL) ? table[idx] : 0;
    sh[t] = v;
    __syncthreads();
    #pragma unroll
    for (int off = 1; off < 256; off <<= 1) {
        int u = (t >= off) ? sh[t - off] : 0;
        __syncthreads();
        sh[t] += u;
        __syncthreads();
    }
    int excl = (t == 0) ? 0 : sh[t - 1];
    if (idx < TBL) table[idx] = part[b] + excl;
}

// ===========================================================================
// K3: atomic-free scatter into bucket-partitioned tmp.
// word0 = (row&127)<<16 | col  (col < 65536), word1 = val bits.
// ===========================================================================
__global__ __launch_bounds__(256) void k3_scatter(
    const int* __restrict__ rows, const int* __restrict__ cols,
    const float* __restrict__ vals, const unsigned short* __restrict__ rank,
    const int* __restrict__ table, int2* __restrict__ tmp)
{
    __shared__ int base[NBUK];
    int b = blockIdx.x, t = threadIdx.x;
    for (int i = t; i < NBUK; i += 256) base[i] = table[i * NBLK1 + b];
    __syncthreads();
    int e0 = b * EPB;
    int e1 = min(e0 + EPB, NE);
    for (int e = e0 + t; e < e1; e += 256) {
        int r = rows[e];
        int pos = base[r >> 7] + (int)rank[e];
        tmp[pos] = make_int2(((r & 127) << 16) | cols[e], __float_as_int(vals[e]));
    }
}

// ===========================================================================
// K4: per-bucket fine sort (128 rows) -> final CSR pairs + rowptr.
// ===========================================================================
__global__ __launch_bounds__(256) void k4_fine(
    const int* __restrict__ table, const int2* __restrict__ tmp,
    int2* __restrict__ pairs, int* __restrict__ rowptr)
{
    __shared__ int cnt[128];
    __shared__ int sh[256];
    __shared__ int nxt[128];
    int k = blockIdx.x, t = threadIdx.x;
    if (t < 128) cnt[t] = 0;
    __syncthreads();
    int base = table[k * NBLK1];
    int end  = (k == NBUK - 1) ? NE : table[(k + 1) * NBLK1];
    for (int e = base + t; e < end; e += 256)
        atomicAdd(&cnt[(tmp[e].x >> 16) & 127], 1);
    __syncthreads();
    sh[t] = (t < 128) ? cnt[t] : 0;
    __syncthreads();
    #pragma unroll
    for (int off = 1; off < 256; off <<= 1) {
        int v = (t >= off) ? sh[t - off] : 0;
        __syncthreads();
        sh[t] += v;
        __syncthreads();
    }
    if (t < 128) {
        int excl = (t == 0) ? 0 : sh[t - 1];
        nxt[t] = base + excl;
        int row = k * 128 + t;
        if (row < N_NODES) rowptr[row] = base + excl;
    }
    if (k == NBUK - 1 && t == 255) rowptr[N_NODES] = NE;
    __syncthreads();
    for (int e = base + t; e < end; e += 256) {
        int2 p = tmp[e];
        int pos = atomicAdd(&nxt[(p.x >> 16) & 127], 1);
        pairs[pos] = make_int2(p.x & 0xFFFF, p.y);
    }
}

// ===========================================================================
// CSR SpMM (gather form, no atomics): y[r,:] = sum_e val_e * x[col_e,:]
// ===========================================================================
template <bool ABS>
__global__ __launch_bounds__(256) void csr_spmm_kernel(
    const int* __restrict__ rowptr, const int2* __restrict__ pairs,
    const float* __restrict__ x, float* __restrict__ y)
{
    int t   = blockIdx.x * 256 + threadIdx.x;
    int r   = t >> 5;
    int sub = t & 31;
    if (r >= N_NODES) return;

    const float4* x4 = (const float4*)x;
    int start = rowptr[r], end = rowptr[r + 1];

    float4 a0 = {0.f, 0.f, 0.f, 0.f};
    float4 a1 = {0.f, 0.f, 0.f, 0.f};
    float4 a2 = {0.f, 0.f, 0.f, 0.f};
    float4 a3 = {0.f, 0.f, 0.f, 0.f};
    int e = start;
    for (; e + 3 < end; e += 4) {
        int2 p0 = pairs[e];
        int2 p1 = pairs[e + 1];
        int2 p2 = pairs[e + 2];
        int2 p3 = pairs[e + 3];
        float4 x0 = x4[(size_t)p0.x * 32 + sub];
        float4 x1 = x4[(size_t)p1.x * 32 + sub];
        float4 x2 = x4[(size_t)p2.x * 32 + sub];
        float4 x3 = x4[(size_t)p3.x * 32 + sub];
        float v0 = __int_as_float(p0.y);
        float v1 = __int_as_float(p1.y);
        float v2 = __int_as_float(p2.y);
        float v3 = __int_as_float(p3.y);
        a0.x += v0 * x0.x; a0.y += v0 * x0.y; a0.z += v0 * x0.z; a0.w += v0 * x0.w;
        a1.x += v1 * x1.x; a1.y += v1 * x1.y; a1.z += v1 * x1.z; a1.w += v1 * x1.w;
        a2.x += v2 * x2.x; a2.y += v2 * x2.y; a2.z += v2 * x2.z; a2.w += v2 * x2.w;
        a3.x += v3 * x3.x; a3.y += v3 * x3.y; a3.z += v3 * x3.z; a3.w += v3 * x3.w;
    }
    for (; e < end; ++e) {
        int2 p0 = pairs[e];
        float4 x0 = x4[(size_t)p0.x * 32 + sub];
        float v0 = __int_as_float(p0.y);
        a0.x += v0 * x0.x; a0.y += v0 * x0.y; a0.z += v0 * x0.z; a0.w += v0 * x0.w;
    }
    float4 acc;
    acc.x = (a0.x + a1.x) + (a2.x + a3.x);
    acc.y = (a0.y + a1.y) + (a2.y + a3.y);
    acc.z = (a0.z + a1.z) + (a2.z + a3.z);
    acc.w = (a0.w + a1.w) + (a2.w + a3.w);
    if (ABS) {
        acc.x = fabsf(acc.x); acc.y = fabsf(acc.y);
        acc.z = fabsf(acc.z); acc.w = fabsf(acc.w);
    }
    ((float4*)(y + (size_t)r * HID))[sub] = acc;
}

// ===========================================================================
// Attention: e[n,b] = dot(relu(pair_b[n]), a); att = softmax over b (6)
// ===========================================================================
__global__ __launch_bounds__(256) void attn_kernel(
    const float* __restrict__ X, const float* __restrict__ B,
    const float* __restrict__ a, float* __restrict__ att)
{
    int wid  = (blockIdx.x * 256 + threadIdx.x) >> 6;
    int lane = threadIdx.x & 63;
    if (wid >= N_NODES) return;

    const float4 av = ((const float4*)a)[lane];
    float e[6];

    if (wid < N_NODES / 2) {
        const float4 p = ((const float4*)(X + (size_t)wid * 256))[lane];
        float s = fmaxf(p.x, 0.f) * av.x + fmaxf(p.y, 0.f) * av.y +
                  fmaxf(p.z, 0.f) * av.z + fmaxf(p.w, 0.f) * av.w;
        #pragma unroll
        for (int m = 1; m < 64; m <<= 1) s += __shfl_xor(s, m);
        #pragma unroll
        for (int b = 0; b < 6; ++b) e[b] = s;
    } else {
        int m = 2 * wid - N_NODES;
        #pragma unroll
        for (int b = 0; b < 6; ++b) {
            const float4 p =
                ((const float4*)(B + (size_t)b * NH + (size_t)m * HID))[lane];
            float s = fmaxf(p.x, 0.f) * av.x + fmaxf(p.y, 0.f) * av.y +
                      fmaxf(p.z, 0.f) * av.z + fmaxf(p.w, 0.f) * av.w;
            #pragma unroll
            for (int k = 1; k < 64; k <<= 1) s += __shfl_xor(s, k);
            e[b] = s;
        }
    }

    if (lane == 0) {
        float mx = e[0];
        #pragma unroll
        for (int b = 1; b < 6; ++b) mx = fmaxf(mx, e[b]);
        float ex[6], sum = 0.f;
        #pragma unroll
        for (int b = 0; b < 6; ++b) { ex[b] = expf(e[b] - mx); sum += ex[b]; }
        float inv = 1.f / sum;
        #pragma unroll
        for (int b = 0; b < 6; ++b) att[(size_t)wid * 6 + b] = ex[b] * inv;
    }
}

// ===========================================================================
// h_prime[n,q] = (1/6) * sum_p att[n,p] * B_{(p*128+q)%6}[n, (p*128+q)/6]
// ===========================================================================
__global__ __launch_bounds__(256) void hprime_kernel(
    const float* __restrict__ B, const float* __restrict__ att,
    float* __restrict__ hp)
{
    int idx = blockIdx.x * 256 + threadIdx.x;
    if (idx >= NH) return;
    int n = idx >> 7;
    int q = idx & 127;
    float s = 0.f;
    #pragma unroll
    for (int p = 0; p < 6; ++p) {
        int f = p * HID + q;
        int j = f % 6;
        int i = f / 6;
        s += att[(size_t)n * 6 + p] * B[(size_t)j * NH + (size_t)n * HID + i];
    }
    hp[idx] = s * (1.0f / 6.0f);
}

// ===========================================================================
// Register-tiled FC: out[n,o] = leaky_relu(dot(in[n,:], W[o,:]) + b[o])
// Block = 128 rows x 128 cols; thread = 8x8 tile (acc[8][8]).
// LDS tiles xs/ws [128][33] (stride 33 -> conflict-free b32 reads).
// Per k: 16 ds_read_b32 feed 64 FMAs -> FMA-bound.
// ===========================================================================
__global__ __launch_bounds__(256) void fc_tile_kernel(
    const float* __restrict__ in, const float* __restrict__ W,
    const float* __restrict__ bias, float* __restrict__ out)
{
    __shared__ float xs[128][33];
    __shared__ float wsm[128][33];
    const int t  = threadIdx.x;
    const int tr = t >> 4;    // 0..15 (row group: rows tr + 16*i)
    const int tc = t & 15;    // 0..15 (col group: cols tc + 16*j)
    const int n0 = blockIdx.x * 128;

    float acc[8][8];
    #pragma unroll
    for (int i = 0; i < 8; ++i)
        #pragma unroll
        for (int j = 0; j < 8; ++j) acc[i][j] = 0.f;

    for (int kc = 0; kc < 4; ++kc) {
        __syncthreads();   // protect previous chunk's reads
        #pragma unroll
        for (int q = 0; q < 4; ++q) {
            int f4  = q * 256 + t;       // 0..1023
            int row = f4 >> 3;           // 0..127
            int kq  = f4 & 7;            // float4 index within 32-k chunk
            int n   = min(n0 + row, N_NODES - 1);
            float4 v = ((const float4*)in)[(size_t)n * 32 + kc * 8 + kq];
            xs[row][kq * 4 + 0] = v.x;
            xs[row][kq * 4 + 1] = v.y;
            xs[row][kq * 4 + 2] = v.z;
            xs[row][kq * 4 + 3] = v.w;
            float4 w = ((const float4*)W)[(size_t)row * 32 + kc * 8 + kq];
            wsm[row][kq * 4 + 0] = w.x;
            wsm[row][kq * 4 + 1] = w.y;
            wsm[row][kq * 4 + 2] = w.z;
            wsm[row][kq * 4 + 3] = w.w;
        }
        __syncthreads();
        #pragma unroll
        for (int k = 0; k < 32; ++k) {
            float xv[8], wv[8];
            #pragma unroll
            for (int i = 0; i < 8; ++i) xv[i] = xs[tr + 16 * i][k];
            #pragma unroll
            for (int j = 0; j < 8; ++j) wv[j] = wsm[tc + 16 * j][k];
            #pragma unroll
            for (int i = 0; i < 8; ++i)
                #pragma unroll
                for (int j = 0; j < 8; ++j)
                    acc[i][j] += xv[i] * wv[j];
        }
    }

    #pragma unroll
    for (int j = 0; j < 8; ++j) {
        int o = tc + 16 * j;
        float bo = bias[o];
        #pragma unroll
        for (int i = 0; i < 8; ++i) {
            int n = n0 + tr + 16 * i;
            if (n < N_NODES) {
                float v = acc[i][j] + bo;
                v = v > 0.f ? v : 0.01f * v;
                out[(size_t)n * HID + o] = v;
            }
        }
    }
}

// ===========================================================================
extern "C" void kernel_launch(void* const* d_in, const int* in_sizes, int n_in,
                              void* d_out, int out_size, void* d_ws, size_t ws_size,
                              hipStream_t stream)
{
    const float* X  = (const float*)d_in[0];
    const float* a  = (const float*)d_in[1];
    const float* W1 = (const float*)d_in[2];
    const float* b1 = (const float*)d_in[3];
    const float* W2 = (const float*)d_in[4];
    const float* b2 = (const float*)d_in[5];
    const int*   op_rows[4] = { (const int*)d_in[6],  (const int*)d_in[9],
                                (const int*)d_in[12], (const int*)d_in[15] };
    const int*   op_cols[4] = { (const int*)d_in[7],  (const int*)d_in[10],
                                (const int*)d_in[13], (const int*)d_in[16] };
    const float* op_vals[4] = { (const float*)d_in[8],  (const float*)d_in[11],
                                (const float*)d_in[14], (const float*)d_in[17] };
    // d_in[18..20] = Psct (unused: withgres=False)

    // ---- workspace layout (4-byte words, keep int2 buffers 8B-aligned) ----
    float* ws = (float*)d_ws;
    float* B     = ws;                                     // 6*NH
    float* att   = B + (size_t)6 * NH;                     // 6*N
    int*   ptr   = (int*)(att + (size_t)6 * N_NODES);      // N+2
    int*   table = ptr + N_NODES + 2;                      // TBL (pad to even)
    int*   part  = table + TBL + 1;                        // 1024
    unsigned short* brnk = (unsigned short*)(part + 1024); // NE ushort = NE/2 words
    int2*  tmp   = (int2*)((int*)brnk + NE / 2);           // NE int2
    int2*  pairs = tmp + NE;                               // NE int2 (shared by all ops)
    // mid aliases tmp+pairs (dead after the last spmm): NE int2 * 2 = 6.4M floats = NH
    float* mid   = (float*)tmp;

    float* hp = (float*)d_out;   // hprime output lives in d_out (fc1 reads it)

    dim3 blk(256);
    const int rg = (N_NODES * 32 + 255) / 256;  // 6250
    const int fg = (N_NODES + 127) / 128;       // 391

    // sorts one operator into (pairs, ptr) — no global atomics anywhere
    auto sort_op = [&](int o) {
        k1_hist<<<NBLK1, blk, 0, stream>>>(op_rows[o], table, brnk);
        s1_partial<<<SB, blk, 0, stream>>>(table, part);
        s2_scan<<<1, 1024, 0, stream>>>(part);
        s3_add<<<SB, blk, 0, stream>>>(table, part);
        k3_scatter<<<NBLK1, blk, 0, stream>>>(op_rows[o], op_cols[o], op_vals[o],
                                              brnk, table, tmp);
        k4_fine<<<NBUK, blk, 0, stream>>>(table, tmp, pairs, ptr);
    };

    // ---- A: sort, then 3 chained hops (CSR dead afterwards -> P's reuse) ----
    sort_op(0);
    csr_spmm_kernel<false><<<rg, blk, 0, stream>>>(ptr, pairs, X,               B + 0 * (size_t)NH);
    csr_spmm_kernel<false><<<rg, blk, 0, stream>>>(ptr, pairs, B + 0 * (size_t)NH, B + 1 * (size_t)NH);
    csr_spmm_kernel<false><<<rg, blk, 0, stream>>>(ptr, pairs, B + 1 * (size_t)NH, B + 2 * (size_t)NH);

    // ---- P1..P3: sort (reusing buffers), spmm with fused abs ----
    for (int i = 0; i < 3; ++i) {
        sort_op(1 + i);
        csr_spmm_kernel<true><<<rg, blk, 0, stream>>>(ptr, pairs, X, B + (size_t)(3 + i) * NH);
    }

    // ---- attention, hprime, register-tiled FCs ----
    attn_kernel<<<(N_NODES + 3) / 4, blk, 0, stream>>>(X, B, a, att);
    hprime_kernel<<<(NH + 255) / 256, blk, 0, stream>>>(B, att, hp);
    fc_tile_kernel<<<fg, blk, 0, stream>>>(hp,  W1, b1, mid);
    fc_tile_kernel<<<fg, blk, 0, stream>>>(mid, W2, b2, (float*)d_out);
}